// Round 4
// baseline (215.297 us; speedup 1.0000x reference)
//
#include <hip/hip_runtime.h>

typedef unsigned short u16;
typedef unsigned int u32;
typedef __bf16 bf16x8 __attribute__((ext_vector_type(8)));
typedef float f32x4 __attribute__((ext_vector_type(4)));
typedef float f32x16 __attribute__((ext_vector_type(16)));
typedef u16 u16x8 __attribute__((ext_vector_type(8)));
typedef u32 u32x2 __attribute__((ext_vector_type(2)));

#define MFMA16(a, b, c) __builtin_amdgcn_mfma_f32_16x16x32_bf16((a), (b), (c), 0, 0, 0)
#define MFMA32(a, b, c) __builtin_amdgcn_mfma_f32_32x32x16_bf16((a), (b), (c), 0, 0, 0)

__device__ __forceinline__ u16 f2bf(float f) {
    unsigned int u = __float_as_uint(f);
    u = (u + 0x7FFF + ((u >> 16) & 1)) >> 16;
    return (u16)u;
}

__device__ __forceinline__ u32 cvtpk(float a, float b) {
    u32 d;
    asm("v_cvt_pk_bf16_f32 %0, %1, %2" : "=v"(d) : "v"(a), "v"(b));
    return d;
}

__device__ __forceinline__ void gld_lds16(const u16* g, u16* l) {
    __builtin_amdgcn_global_load_lds(
        (const __attribute__((address_space(1))) unsigned int*)g,
        (__attribute__((address_space(3))) unsigned int*)l, 16, 0, 0);
}

// ---------------- fp32 -> bf16 cast ----------------
__global__ __launch_bounds__(256) void cvt_bf16(const float* __restrict__ in,
                                                u16* __restrict__ out, int n4) {
    int idx = blockIdx.x * blockDim.x + threadIdx.x;
    int stride = gridDim.x * blockDim.x;
    for (int i = idx; i < n4; i += stride) {
        float4 v = reinterpret_cast<const float4*>(in)[i];
        ushort4 o;
        o.x = f2bf(v.x); o.y = f2bf(v.y); o.z = f2bf(v.z); o.w = f2bf(v.w);
        reinterpret_cast<ushort4*>(out)[i] = o;
    }
}

// ---------------- zero fill (f32, vectorized) ----------------
__global__ __launch_bounds__(256) void zero_f32(float4* __restrict__ p, int n4) {
    int idx = blockIdx.x * blockDim.x + threadIdx.x;
    int stride = gridDim.x * blockDim.x;
    float4 z = {0.f, 0.f, 0.f, 0.f};
    for (int i = idx; i < n4; i += stride) p[i] = z;
}

// ---------------- bf16 GEMM: C[M,N] (+)= A[M,K] * B[N,K]^T, split-K ----------------
// blockIdx.y = K-slice. SPLITK>1: epilogue atomicAdd (C must be zeroed first).
template <int SPLITK>
__global__ __launch_bounds__(256) void gemm_bt(const u16* __restrict__ A,
                                               const u16* __restrict__ B,
                                               float* __restrict__ C,
                                               int M, int N, int K) {
    __shared__ __align__(16) u16 As[2][128 * 32];
    __shared__ __align__(16) u16 Bs[2][128 * 32];

    int nbn = N >> 7;
    int nwg = (M >> 7) * nbn;
    int bid = blockIdx.x;
    int cpx = nwg >> 3;
    int wg = (bid & 7) * cpx + (bid >> 3);   // XCD swizzle (gridX % 8 == 0)
    int tm = wg / nbn, tn = wg % nbn;
    int m0 = tm << 7, n0 = tn << 7;

    int Ks = K / SPLITK;
    int kbase = blockIdx.y * Ks;

    int t = threadIdx.x;
    int w = t >> 6, l = t & 63, lrow = l & 15, lhi = l >> 4;
    int wr = w >> 1, wc = w & 1;

    int e0 = t * 8;
    int row0 = e0 >> 5, col0 = e0 & 31;

    const u16* Ag = A + (size_t)m0 * K + kbase;
    const u16* Bg = B + (size_t)n0 * K + kbase;

    auto stage = [&](int sbuf, int kt) {
        int k0 = kt << 5;
        gld_lds16(Ag + (size_t)row0 * K + k0 + col0, &As[sbuf][e0]);
        gld_lds16(Ag + (size_t)(row0 + 64) * K + k0 + col0, &As[sbuf][e0 + 2048]);
        gld_lds16(Bg + (size_t)row0 * K + k0 + col0, &Bs[sbuf][e0]);
        gld_lds16(Bg + (size_t)(row0 + 64) * K + k0 + col0, &Bs[sbuf][e0 + 2048]);
    };

    f32x4 acc[4][4] = {};
    int NT = Ks >> 5;
    stage(0, 0);
    __syncthreads();
    int buf = 0;
    for (int kt = 0; kt < NT; ++kt) {
        if (kt + 1 < NT) stage(buf ^ 1, kt + 1);
        bf16x8 af[4], bfr[4];
#pragma unroll
        for (int i = 0; i < 4; ++i) {
            af[i]  = *(const bf16x8*)&As[buf][(wr * 64 + i * 16 + lrow) * 32 + lhi * 8];
            bfr[i] = *(const bf16x8*)&Bs[buf][(wc * 64 + i * 16 + lrow) * 32 + lhi * 8];
        }
#pragma unroll
        for (int i = 0; i < 4; ++i)
#pragma unroll
            for (int j = 0; j < 4; ++j)
                acc[i][j] = MFMA16(af[i], bfr[j], acc[i][j]);
        __syncthreads();
        buf ^= 1;
    }
#pragma unroll
    for (int i = 0; i < 4; ++i) {
#pragma unroll
        for (int j = 0; j < 4; ++j) {
            int crow = m0 + wr * 64 + i * 16 + lhi * 4;
            int ccol = n0 + wc * 64 + j * 16 + lrow;
            float* cp = C + (size_t)crow * N + ccol;
#pragma unroll
            for (int r2 = 0; r2 < 4; ++r2) {
                if (SPLITK == 1) cp[(size_t)r2 * N] = acc[i][j][r2];
                else atomicAdd(cp + (size_t)r2 * N, acc[i][j][r2]);
            }
        }
    }
}

// ---------------- qkv post: RMSNorm + RoPE + cast + head-major layout ----------------
__global__ __launch_bounds__(256) void qkv_post(const float* __restrict__ qkv,
                                                const float* __restrict__ qw,
                                                const float* __restrict__ kw,
                                                u16* __restrict__ qb,
                                                u16* __restrict__ kb,
                                                u16* __restrict__ vb) {
    int s = blockIdx.x;
    int t = threadIdx.x, w = t >> 6, lane = t & 63;
    const float* row = qkv + (size_t)s * 3072;
    int d2 = lane & 31;
    float inv = exp2f(-(float)d2 * (13.287712379549449f / 32.0f));
    float ang = (float)s * inv;
    float cs = cosf(ang), sn = sinf(ang);
    for (int h = w; h < 48; h += 4) {
        float v = row[h * 64 + lane];
        if (h < 40) {
            float ss = v * v;
#pragma unroll
            for (int m = 32; m; m >>= 1) ss += __shfl_xor(ss, m);
            float rms = rsqrtf(ss * (1.0f / 64.0f) + 1e-6f);
            float wgt = (h < 32) ? qw[lane] : kw[lane];
            v = v * rms * wgt;
            float part = __shfl_xor(v, 32);
            float rot = (lane < 32) ? -part : part;
            v = v * cs + rot * sn;
            if (h < 32)
                qb[((size_t)h * 2048 + s) * 64 + lane] = f2bf(v);
            else
                kb[((size_t)(h - 32) * 2048 + s) * 64 + lane] = f2bf(v);
        } else {
            vb[((size_t)(h - 40) * 2048 + s) * 64 + lane] = f2bf(v);
        }
    }
}

// ---------------- V transpose: vb[kv][s][d] -> vt[kv][d][s] ----------------
__global__ __launch_bounds__(256) void transpose_v(const u16* __restrict__ vb,
                                                   u16* __restrict__ vt) {
    int kv = blockIdx.y;
    int s0 = blockIdx.x * 256;
    __shared__ __align__(16) u16 tile[64][256];
    int t = threadIdx.x;
    int sl = t >> 3;
    int d0 = (t & 7) * 8;
#pragma unroll
    for (int j = 0; j < 8; ++j) {
        int s = sl + j * 32;
        u16x8 v = *(const u16x8*)(vb + ((size_t)kv * 2048 + s0 + s) * 64 + d0);
#pragma unroll
        for (int e = 0; e < 8; ++e) tile[d0 + e][s] = v[e];
    }
    __syncthreads();
    int d = t >> 2;
    int so = (t & 3) * 64;
#pragma unroll
    for (int j = 0; j < 8; ++j) {
        int s_local = so + j * 8;
        *(u16x8*)(vt + ((size_t)kv * 64 + d) * 2048 + s0 + s_local) =
            *(const u16x8*)&tile[d][s_local];
    }
}

// ---------------- flash attention v2: swapped-operand 32x32 MFMA ----------------
__global__ __launch_bounds__(256) void attn_fa2(const u16* __restrict__ qb,
                                                const u16* __restrict__ kb,
                                                const u16* __restrict__ vt,
                                                u16* __restrict__ ab) {
    const float C = 0.18033688011112042f;  // 0.125 * log2(e)
    int h = blockIdx.y, kv = h >> 2;
    int t = threadIdx.x, w = t >> 6, l = t & 63;
    int lq = l & 31, hi = l >> 5;
    int qlo = blockIdx.x * 128 + w * 32;
    __shared__ u16 sm[4][32][66];

    const u16* qrow = qb + ((size_t)h * 2048 + qlo + lq) * 64 + hi * 8;
    bf16x8 qf[4];
#pragma unroll
    for (int dk = 0; dk < 4; ++dk) qf[dk] = *(const bf16x8*)(qrow + dk * 16);

    f32x16 oa = {}, ob = {};
    float m = 0.f, lsum = 0.f;

    int kstart = qlo - 511; if (kstart < 0) kstart = 0;
    int kt0 = kstart >> 5, kt1 = qlo >> 5;
    const u16* kb_h = kb + (size_t)kv * 2048 * 64;
    const u16* vt_h = vt + (size_t)kv * 64 * 2048;

    for (int kt = kt0; kt <= kt1; ++kt) {
        int k0 = kt << 5;
        const u16* krow = kb_h + (size_t)(k0 + lq) * 64 + hi * 8;
        bf16x8 kf0 = *(const bf16x8*)(krow);
        bf16x8 kf1 = *(const bf16x8*)(krow + 16);
        bf16x8 kf2 = *(const bf16x8*)(krow + 32);
        bf16x8 kf3 = *(const bf16x8*)(krow + 48);
        const u16* vrow = vt_h + (size_t)lq * 2048 + k0 + hi * 8;
        bf16x8 va0 = *(const bf16x8*)(vrow);
        bf16x8 va1 = *(const bf16x8*)(vrow + 16);
        bf16x8 vb0 = *(const bf16x8*)(vrow + 32 * 2048);
        bf16x8 vb1 = *(const bf16x8*)(vrow + 32 * 2048 + 16);

        f32x16 s = {};
        s = MFMA32(kf0, qf[0], s);
        s = MFMA32(kf1, qf[1], s);
        s = MFMA32(kf2, qf[2], s);
        s = MFMA32(kf3, qf[3], s);

        bool edge = (k0 + 31 > qlo) || (qlo + 31 - k0 >= 512);
        if (edge) {
            int q = qlo + lq;
#pragma unroll
            for (int r = 0; r < 16; ++r) {
                int k = k0 + (r & 3) + 8 * (r >> 2) + 4 * hi;
                if (!((unsigned)(q - k) < 512u)) s[r] = -1e30f;
            }
        }
        float tm = s[0];
#pragma unroll
        for (int r = 1; r < 16; ++r) tm = fmaxf(tm, s[r]);
        tm = fmaxf(tm, __shfl_xor(tm, 32));
        float mnew = fmaxf(m, tm);          // m >= 0 always
        float mc = mnew * C;
        float sf = exp2f(m * C - mc);
        m = mnew;
        float p[16];
        float rs = 0.f;
#pragma unroll
        for (int r = 0; r < 16; ++r) {
            p[r] = exp2f(fmaf(s[r], C, -mc));
            rs += p[r];
        }
        rs += __shfl_xor(rs, 32);
        lsum = lsum * sf + rs;
#pragma unroll
        for (int r = 0; r < 16; ++r) { oa[r] *= sf; ob[r] *= sf; }

        u32 pk0 = cvtpk(p[0], p[1]),   pk1 = cvtpk(p[2], p[3]);
        u32 pk2 = cvtpk(p[4], p[5]),   pk3 = cvtpk(p[6], p[7]);
        u32 pk4 = cvtpk(p[8], p[9]),   pk5 = cvtpk(p[10], p[11]);
        u32 pk6 = cvtpk(p[12], p[13]), pk7 = cvtpk(p[14], p[15]);
        u32x2 r02 = __builtin_amdgcn_permlane32_swap(pk0, pk2, false, false);
        u32x2 r13 = __builtin_amdgcn_permlane32_swap(pk1, pk3, false, false);
        u32x2 r46 = __builtin_amdgcn_permlane32_swap(pk4, pk6, false, false);
        u32x2 r57 = __builtin_amdgcn_permlane32_swap(pk5, pk7, false, false);
        bf16x8 b0, b1;
        {
            u32* bp = (u32*)&b0;
            bp[0] = r02[0]; bp[1] = r13[0]; bp[2] = r02[1]; bp[3] = r13[1];
            u32* bq = (u32*)&b1;
            bq[0] = r46[0]; bq[1] = r57[0]; bq[2] = r46[1]; bq[3] = r57[1];
        }
        oa = MFMA32(va0, b0, oa);
        oa = MFMA32(va1, b1, oa);
        ob = MFMA32(vb0, b0, ob);
        ob = MFMA32(vb1, b1, ob);
    }

    float inv = 1.0f / lsum;
#pragma unroll
    for (int rp = 0; rp < 8; ++rp) {
        int r = rp * 2;
        int d = (r & 3) + 8 * (r >> 2) + 4 * hi;
        *(u32*)&sm[w][lq][d]      = cvtpk(oa[r] * inv, oa[r + 1] * inv);
        *(u32*)&sm[w][lq][d + 32] = cvtpk(ob[r] * inv, ob[r + 1] * inv);
    }
    asm volatile("s_waitcnt lgkmcnt(0)" ::: "memory");
    int qr = l >> 1, dbase = (l & 1) * 32;
    size_t orow = (size_t)(qlo + qr) * 2048 + h * 64 + dbase;
#pragma unroll
    for (int c2 = 0; c2 < 8; ++c2) {
        u32 w0 = *(const u32*)&sm[w][qr][dbase + c2 * 4];
        u32 w1 = *(const u32*)&sm[w][qr][dbase + c2 * 4 + 2];
        u32x2 val = { w0, w1 };
        *(u32x2*)(ab + orow + c2 * 4) = val;
    }
}

// ---------------- launch ----------------
extern "C" void kernel_launch(void* const* d_in, const int* in_sizes, int n_in,
                              void* d_out, int out_size, void* d_ws, size_t ws_size,
                              hipStream_t stream) {
    const float* x     = (const float*)d_in[0];
    const float* w_qkv = (const float*)d_in[1];
    const float* w_out = (const float*)d_in[2];
    const float* qw    = (const float*)d_in[3];
    const float* kw    = (const float*)d_in[4];
    float* out = (float*)d_out;

    char* ws = (char*)d_ws;
    u16*   x_b    = (u16*)(ws);
    u16*   wB     = (u16*)(ws + 8388608);
    float* qkv    = (float*)(ws + 20971520);
    u16*   q_b    = (u16*)(ws + 46137344);
    u16*   k_b    = (u16*)(ws + 54525952);
    u16*   v_b    = (u16*)(ws + 56623104);
    u16*   v_t    = (u16*)(ws + 58720256);
    u16*   attn_b = x_b;

    cvt_bf16<<<2048, 256, 0, stream>>>(x, x_b, 2048 * 2048 / 4);
    cvt_bf16<<<2048, 256, 0, stream>>>(w_qkv, wB, 3072 * 2048 / 4);
    zero_f32<<<1024, 256, 0, stream>>>((float4*)qkv, 2048 * 3072 / 4);
    gemm_bt<2><<<dim3(384, 2), 256, 0, stream>>>(x_b, wB, qkv, 2048, 3072, 2048);
    qkv_post<<<2048, 256, 0, stream>>>(qkv, qw, kw, q_b, k_b, v_b);
    transpose_v<<<dim3(8, 8), 256, 0, stream>>>(v_b, v_t);
    attn_fa2<<<dim3(16, 32), 256, 0, stream>>>(q_b, k_b, v_t, attn_b);
    cvt_bf16<<<2048, 256, 0, stream>>>(w_out, wB, 2048 * 2048 / 4);
    zero_f32<<<1024, 256, 0, stream>>>((float4*)out, 2048 * 2048 / 4);
    gemm_bt<4><<<dim3(256, 4), 256, 0, stream>>>(attn_b, wB, out, 2048, 2048, 2048);
}

// Round 5
// 145.612 us; speedup vs baseline: 1.4786x; 1.4786x over previous
//
#include <hip/hip_runtime.h>

typedef unsigned short u16;
typedef unsigned int u32;
typedef __bf16 bf16x8 __attribute__((ext_vector_type(8)));
typedef float f32x4 __attribute__((ext_vector_type(4)));
typedef float f32x16 __attribute__((ext_vector_type(16)));
typedef u16 u16x8 __attribute__((ext_vector_type(8)));
typedef u32 u32x2 __attribute__((ext_vector_type(2)));

#define MFMA16(a, b, c) __builtin_amdgcn_mfma_f32_16x16x32_bf16((a), (b), (c), 0, 0, 0)
#define MFMA32(a, b, c) __builtin_amdgcn_mfma_f32_32x32x16_bf16((a), (b), (c), 0, 0, 0)

__device__ __forceinline__ u16 f2bf(float f) {
    unsigned int u = __float_as_uint(f);
    u = (u + 0x7FFF + ((u >> 16) & 1)) >> 16;
    return (u16)u;
}

__device__ __forceinline__ u32 cvtpk(float a, float b) {
    u32 d;
    asm("v_cvt_pk_bf16_f32 %0, %1, %2" : "=v"(d) : "v"(a), "v"(b));
    return d;
}

__device__ __forceinline__ void gld_lds16(const u16* g, u16* l) {
    __builtin_amdgcn_global_load_lds(
        (const __attribute__((address_space(1))) unsigned int*)g,
        (__attribute__((address_space(3))) unsigned int*)l, 16, 0, 0);
}

// ---------------- fp32 -> bf16 cast ----------------
__global__ __launch_bounds__(256) void cvt_bf16(const float* __restrict__ in,
                                                u16* __restrict__ out, int n4) {
    int idx = blockIdx.x * blockDim.x + threadIdx.x;
    int stride = gridDim.x * blockDim.x;
    for (int i = idx; i < n4; i += stride) {
        float4 v = reinterpret_cast<const float4*>(in)[i];
        ushort4 o;
        o.x = f2bf(v.x); o.y = f2bf(v.y); o.z = f2bf(v.z); o.w = f2bf(v.w);
        reinterpret_cast<ushort4*>(out)[i] = o;
    }
}

// ---------------- partial-sum reduce: o = a + b ----------------
__global__ __launch_bounds__(256) void reduce_add(const float4* __restrict__ a,
                                                  const float4* __restrict__ b,
                                                  float4* __restrict__ o, int n4) {
    int idx = blockIdx.x * blockDim.x + threadIdx.x;
    int stride = gridDim.x * blockDim.x;
    for (int i = idx; i < n4; i += stride) {
        float4 va = a[i], vb = b[i];
        float4 vo = {va.x + vb.x, va.y + vb.y, va.z + vb.z, va.w + vb.w};
        o[i] = vo;
    }
}

// ---------------- bf16 GEMM, split-K into per-slice partial buffers ----------------
// blockIdx.y = K-slice; slice y writes C + y*M*N (plain stores, no atomics).
template <int SPLITK>
__global__ __launch_bounds__(256) void gemm_bt(const u16* __restrict__ A,
                                               const u16* __restrict__ B,
                                               float* __restrict__ C,
                                               int M, int N, int K) {
    __shared__ __align__(16) u16 As[2][128 * 32];
    __shared__ __align__(16) u16 Bs[2][128 * 32];

    int nbn = N >> 7;
    int bid = blockIdx.x;
    int nwg = (M >> 7) * nbn;
    int cpx = nwg >> 3;
    int wg = (bid & 7) * cpx + (bid >> 3);   // XCD swizzle (gridX % 8 == 0)
    int tm = wg / nbn, tn = wg % nbn;
    int m0 = tm << 7, n0 = tn << 7;

    int Ks = K / SPLITK;
    int kbase = blockIdx.y * Ks;
    float* Cs = C + (size_t)blockIdx.y * ((size_t)M * N);

    int t = threadIdx.x;
    int w = t >> 6, l = t & 63, lrow = l & 15, lhi = l >> 4;
    int wr = w >> 1, wc = w & 1;

    int e0 = t * 8;
    int row0 = e0 >> 5, col0 = e0 & 31;

    const u16* Ag = A + (size_t)m0 * K + kbase;
    const u16* Bg = B + (size_t)n0 * K + kbase;

    auto stage = [&](int sbuf, int kt) {
        int k0 = kt << 5;
        gld_lds16(Ag + (size_t)row0 * K + k0 + col0, &As[sbuf][e0]);
        gld_lds16(Ag + (size_t)(row0 + 64) * K + k0 + col0, &As[sbuf][e0 + 2048]);
        gld_lds16(Bg + (size_t)row0 * K + k0 + col0, &Bs[sbuf][e0]);
        gld_lds16(Bg + (size_t)(row0 + 64) * K + k0 + col0, &Bs[sbuf][e0 + 2048]);
    };

    f32x4 acc[4][4] = {};
    int NT = Ks >> 5;
    stage(0, 0);
    __syncthreads();
    int buf = 0;
    for (int kt = 0; kt < NT; ++kt) {
        if (kt + 1 < NT) stage(buf ^ 1, kt + 1);
        bf16x8 af[4], bfr[4];
#pragma unroll
        for (int i = 0; i < 4; ++i) {
            af[i]  = *(const bf16x8*)&As[buf][(wr * 64 + i * 16 + lrow) * 32 + lhi * 8];
            bfr[i] = *(const bf16x8*)&Bs[buf][(wc * 64 + i * 16 + lrow) * 32 + lhi * 8];
        }
#pragma unroll
        for (int i = 0; i < 4; ++i)
#pragma unroll
            for (int j = 0; j < 4; ++j)
                acc[i][j] = MFMA16(af[i], bfr[j], acc[i][j]);
        __syncthreads();
        buf ^= 1;
    }
#pragma unroll
    for (int i = 0; i < 4; ++i) {
#pragma unroll
        for (int j = 0; j < 4; ++j) {
            int crow = m0 + wr * 64 + i * 16 + lhi * 4;
            int ccol = n0 + wc * 64 + j * 16 + lrow;
            float* cp = Cs + (size_t)crow * N + ccol;
#pragma unroll
            for (int r2 = 0; r2 < 4; ++r2) cp[(size_t)r2 * N] = acc[i][j][r2];
        }
    }
}

// ---------------- qkv post: partial-add + RMSNorm + RoPE + cast + head-major ----------------
__global__ __launch_bounds__(256) void qkv_post(const float* __restrict__ qkv0,
                                                const float* __restrict__ qkv1,
                                                const float* __restrict__ qw,
                                                const float* __restrict__ kw,
                                                u16* __restrict__ qb,
                                                u16* __restrict__ kb,
                                                u16* __restrict__ vb) {
    int s = blockIdx.x;
    int t = threadIdx.x, w = t >> 6, lane = t & 63;
    const float* row0 = qkv0 + (size_t)s * 3072;
    const float* row1 = qkv1 + (size_t)s * 3072;
    int d2 = lane & 31;
    float inv = exp2f(-(float)d2 * (13.287712379549449f / 32.0f));
    float ang = (float)s * inv;
    float cs = cosf(ang), sn = sinf(ang);
    for (int h = w; h < 48; h += 4) {
        float v = row0[h * 64 + lane] + row1[h * 64 + lane];
        if (h < 40) {
            float ss = v * v;
#pragma unroll
            for (int m = 32; m; m >>= 1) ss += __shfl_xor(ss, m);
            float rms = rsqrtf(ss * (1.0f / 64.0f) + 1e-6f);
            float wgt = (h < 32) ? qw[lane] : kw[lane];
            v = v * rms * wgt;
            float part = __shfl_xor(v, 32);
            float rot = (lane < 32) ? -part : part;
            v = v * cs + rot * sn;
            if (h < 32)
                qb[((size_t)h * 2048 + s) * 64 + lane] = f2bf(v);
            else
                kb[((size_t)(h - 32) * 2048 + s) * 64 + lane] = f2bf(v);
        } else {
            vb[((size_t)(h - 40) * 2048 + s) * 64 + lane] = f2bf(v);
        }
    }
}

// ---------------- V transpose: vb[kv][s][d] -> vt[kv][d][s] ----------------
__global__ __launch_bounds__(256) void transpose_v(const u16* __restrict__ vb,
                                                   u16* __restrict__ vt) {
    int kv = blockIdx.y;
    int s0 = blockIdx.x * 256;
    __shared__ __align__(16) u16 tile[64][256];
    int t = threadIdx.x;
    int sl = t >> 3;
    int d0 = (t & 7) * 8;
#pragma unroll
    for (int j = 0; j < 8; ++j) {
        int s = sl + j * 32;
        u16x8 v = *(const u16x8*)(vb + ((size_t)kv * 2048 + s0 + s) * 64 + d0);
#pragma unroll
        for (int e = 0; e < 8; ++e) tile[d0 + e][s] = v[e];
    }
    __syncthreads();
    int d = t >> 2;
    int so = (t & 3) * 64;
#pragma unroll
    for (int j = 0; j < 8; ++j) {
        int s_local = so + j * 8;
        *(u16x8*)(vt + ((size_t)kv * 64 + d) * 2048 + s0 + s_local) =
            *(const u16x8*)&tile[d][s_local];
    }
}

// ---------------- flash attention v2: swapped-operand 32x32 MFMA ----------------
__global__ __launch_bounds__(256) void attn_fa2(const u16* __restrict__ qb,
                                                const u16* __restrict__ kb,
                                                const u16* __restrict__ vt,
                                                u16* __restrict__ ab) {
    const float C = 0.18033688011112042f;  // 0.125 * log2(e)
    int h = blockIdx.y, kv = h >> 2;
    int t = threadIdx.x, w = t >> 6, l = t & 63;
    int lq = l & 31, hi = l >> 5;
    int qlo = blockIdx.x * 128 + w * 32;
    __shared__ u16 sm[4][32][66];

    const u16* qrow = qb + ((size_t)h * 2048 + qlo + lq) * 64 + hi * 8;
    bf16x8 qf[4];
#pragma unroll
    for (int dk = 0; dk < 4; ++dk) qf[dk] = *(const bf16x8*)(qrow + dk * 16);

    f32x16 oa = {}, ob = {};
    float m = 0.f, lsum = 0.f;

    int kstart = qlo - 511; if (kstart < 0) kstart = 0;
    int kt0 = kstart >> 5, kt1 = qlo >> 5;
    const u16* kb_h = kb + (size_t)kv * 2048 * 64;
    const u16* vt_h = vt + (size_t)kv * 64 * 2048;

    for (int kt = kt0; kt <= kt1; ++kt) {
        int k0 = kt << 5;
        const u16* krow = kb_h + (size_t)(k0 + lq) * 64 + hi * 8;
        bf16x8 kf0 = *(const bf16x8*)(krow);
        bf16x8 kf1 = *(const bf16x8*)(krow + 16);
        bf16x8 kf2 = *(const bf16x8*)(krow + 32);
        bf16x8 kf3 = *(const bf16x8*)(krow + 48);
        const u16* vrow = vt_h + (size_t)lq * 2048 + k0 + hi * 8;
        bf16x8 va0 = *(const bf16x8*)(vrow);
        bf16x8 va1 = *(const bf16x8*)(vrow + 16);
        bf16x8 vb0 = *(const bf16x8*)(vrow + 32 * 2048);
        bf16x8 vb1 = *(const bf16x8*)(vrow + 32 * 2048 + 16);

        f32x16 s = {};
        s = MFMA32(kf0, qf[0], s);
        s = MFMA32(kf1, qf[1], s);
        s = MFMA32(kf2, qf[2], s);
        s = MFMA32(kf3, qf[3], s);

        bool edge = (k0 + 31 > qlo) || (qlo + 31 - k0 >= 512);
        if (edge) {
            int q = qlo + lq;
#pragma unroll
            for (int r = 0; r < 16; ++r) {
                int k = k0 + (r & 3) + 8 * (r >> 2) + 4 * hi;
                if (!((unsigned)(q - k) < 512u)) s[r] = -1e30f;
            }
        }
        float tm = s[0];
#pragma unroll
        for (int r = 1; r < 16; ++r) tm = fmaxf(tm, s[r]);
        tm = fmaxf(tm, __shfl_xor(tm, 32));
        float mnew = fmaxf(m, tm);          // m >= 0 always
        float mc = mnew * C;
        float sf = exp2f(m * C - mc);
        m = mnew;
        float p[16];
        float rs = 0.f;
#pragma unroll
        for (int r = 0; r < 16; ++r) {
            p[r] = exp2f(fmaf(s[r], C, -mc));
            rs += p[r];
        }
        rs += __shfl_xor(rs, 32);
        lsum = lsum * sf + rs;
#pragma unroll
        for (int r = 0; r < 16; ++r) { oa[r] *= sf; ob[r] *= sf; }

        u32 pk0 = cvtpk(p[0], p[1]),   pk1 = cvtpk(p[2], p[3]);
        u32 pk2 = cvtpk(p[4], p[5]),   pk3 = cvtpk(p[6], p[7]);
        u32 pk4 = cvtpk(p[8], p[9]),   pk5 = cvtpk(p[10], p[11]);
        u32 pk6 = cvtpk(p[12], p[13]), pk7 = cvtpk(p[14], p[15]);
        u32x2 r02 = __builtin_amdgcn_permlane32_swap(pk0, pk2, false, false);
        u32x2 r13 = __builtin_amdgcn_permlane32_swap(pk1, pk3, false, false);
        u32x2 r46 = __builtin_amdgcn_permlane32_swap(pk4, pk6, false, false);
        u32x2 r57 = __builtin_amdgcn_permlane32_swap(pk5, pk7, false, false);
        bf16x8 b0, b1;
        {
            u32* bp = (u32*)&b0;
            bp[0] = r02[0]; bp[1] = r13[0]; bp[2] = r02[1]; bp[3] = r13[1];
            u32* bq = (u32*)&b1;
            bq[0] = r46[0]; bq[1] = r57[0]; bq[2] = r46[1]; bq[3] = r57[1];
        }
        oa = MFMA32(va0, b0, oa);
        oa = MFMA32(va1, b1, oa);
        ob = MFMA32(vb0, b0, ob);
        ob = MFMA32(vb1, b1, ob);
    }

    float inv = 1.0f / lsum;
#pragma unroll
    for (int rp = 0; rp < 8; ++rp) {
        int r = rp * 2;
        int d = (r & 3) + 8 * (r >> 2) + 4 * hi;
        *(u32*)&sm[w][lq][d]      = cvtpk(oa[r] * inv, oa[r + 1] * inv);
        *(u32*)&sm[w][lq][d + 32] = cvtpk(ob[r] * inv, ob[r + 1] * inv);
    }
    asm volatile("s_waitcnt lgkmcnt(0)" ::: "memory");
    int qr = l >> 1, dbase = (l & 1) * 32;
    size_t orow = (size_t)(qlo + qr) * 2048 + h * 64 + dbase;
#pragma unroll
    for (int c2 = 0; c2 < 8; ++c2) {
        u32 w0 = *(const u32*)&sm[w][qr][dbase + c2 * 4];
        u32 w1 = *(const u32*)&sm[w][qr][dbase + c2 * 4 + 2];
        u32x2 val = { w0, w1 };
        *(u32x2*)(ab + orow + c2 * 4) = val;
    }
}

// ---------------- launch ----------------
extern "C" void kernel_launch(void* const* d_in, const int* in_sizes, int n_in,
                              void* d_out, int out_size, void* d_ws, size_t ws_size,
                              hipStream_t stream) {
    const float* x     = (const float*)d_in[0];
    const float* w_qkv = (const float*)d_in[1];
    const float* w_out = (const float*)d_in[2];
    const float* qw    = (const float*)d_in[3];
    const float* kw    = (const float*)d_in[4];
    float* out = (float*)d_out;

    char* ws = (char*)d_ws;
    // liveness-overlaid layout (peak 71.3 MB):
    u16*   x_b    = (u16*)(ws);               // 8 MB, dead after gemm1
    u16*   wB     = (u16*)(ws + 8388608);     // 12.6 MB, dead after gemm1; recast for gemm2
    u16*   q_b    = (u16*)(ws);               // overlays x_b
    u16*   k_b    = (u16*)(ws + 8388608);     // 2 MB, overlays wB
    u16*   v_b    = (u16*)(ws + 10485760);    // 2 MB
    u16*   v_t    = (u16*)(ws + 12582912);    // 2 MB (dead before w_out recast)
    float* P0     = (float*)(ws + 20971520);  // gemm1 partials: 2 x 25.17 MB (contiguous)
    float* O0     = (float*)(ws + 20971520);  // gemm2 partials: 2 x 16.78 MB (reuse P region)
    float* O1     = (float*)(ws + 37748736);
    u16*   attn_b = (u16*)(ws + 54525952);    // 8 MB

    cvt_bf16<<<2048, 256, 0, stream>>>(x, x_b, 2048 * 2048 / 4);
    cvt_bf16<<<2048, 256, 0, stream>>>(w_qkv, wB, 3072 * 2048 / 4);
    gemm_bt<2><<<dim3(384, 2), 256, 0, stream>>>(x_b, wB, P0, 2048, 3072, 2048);
    qkv_post<<<2048, 256, 0, stream>>>(P0, P0 + (size_t)2048 * 3072, qw, kw, q_b, k_b, v_b);
    transpose_v<<<dim3(8, 8), 256, 0, stream>>>(v_b, v_t);
    attn_fa2<<<dim3(16, 32), 256, 0, stream>>>(q_b, k_b, v_t, attn_b);
    cvt_bf16<<<2048, 256, 0, stream>>>(w_out, wB, 2048 * 2048 / 4);
    gemm_bt<2><<<dim3(256, 2), 256, 0, stream>>>(attn_b, wB, O0, 2048, 2048, 2048);
    reduce_add<<<1024, 256, 0, stream>>>((const float4*)O0, (const float4*)O1,
                                         (float4*)out, 2048 * 2048 / 4);
}